// Round 3
// baseline (1259.477 us; speedup 1.0000x reference)
//
#include <hip/hip_runtime.h>

#define B_ 64
#define Q_ 64
#define L_ 8192
#define KCONV 51
#define HC 26
#define HT 251

#define NCH2 34               // K-chunks of 16 covering taps (with -6 shift, i up to 31)
// ---- workspace layout (bytes), total 73,531,904 <= proven-safe 73,662,464 ----
#define TA_OFF 512            // PAR: a[64] floats @0, scale @64, kc[51] @65..115
#define S_OFF  2228736        // 512 + 64*34*64*16
#define RSB    17408          // S row: 512 left pad + 16384 data + 512 right pad

// XOR swizzle: bits [9:7] -> [6:4]; line(128B)-preserving involution
#define SWZ(a) ((a) ^ ((((a) >> 7) & 7) << 4))

typedef _Float16 f16x8 __attribute__((ext_vector_type(8)));
typedef float f32x16 __attribute__((ext_vector_type(16)));

__device__ __forceinline__ float sigm(float v) {
    return 1.0f / (1.0f + __expf(-v));
}

// ---------------- kernel 1: derived parameters + 32x32 Toeplitz A-table ----------------
// blocks 0..63: TA2[q][c][lane] = 8 halves of A_c[i=lane&31, kappa=8*(lane>>5)+jj]
//               = kt_q[16c + 8*(lane>>5) + jj - (lane&31) - 6]
__global__ __launch_bounds__(256) void k_params(const float* __restrict__ cwh,
                                                const float* __restrict__ tcw,
                                                const float* __restrict__ araw,
                                                float* __restrict__ ws) {
    const int tid = threadIdx.x;
    const int q = blockIdx.x;
    char* wsb = (char*)ws;
    if (q < Q_) {
        for (int idx = tid; idx < NCH2 * 64; idx += 256) {
            int c = idx >> 6, lane = idx & 63;
            int hi = lane >> 5, i = lane & 31;
            int mbase = 16 * c + 8 * hi - i - 6;
            f16x8 hv;
            #pragma unroll
            for (int jj = 0; jj < 8; jj++) {
                int m = mbase + jj;
                float v = 0.0f;
                if (m >= 0 && m <= 500) {
                    int hh = (m <= 250) ? m : (500 - m);
                    v = sigm(tcw[q * HT + hh]);
                }
                hv[jj] = (_Float16)v;
            }
            *(f16x8*)(wsb + TA_OFF + ((size_t)q * (NCH2 * 64) + idx) * 16) = hv;
        }
    } else {
        if (tid < Q_) ws[tid] = sigm(araw[tid]);
        if (tid < KCONV) ws[65 + tid] = cwh[tid < HC ? tid : (KCONV - 1 - tid)];
        __syncthreads();
        if (tid == 0) {
            float p = 1.0f;
            for (int j = 0; j < Q_; j++) p *= ws[j];
            float peak = sigm(tcw[(Q_ - 1) * HT + 250]);
            ws[64] = 1.0f / (peak * p);
        }
    }
}

// ---------------- kernel 2: conv51 + softmax, no LDS (register windows) ----------------
// 512 threads, one block per (b,q) row; lane handles 4 clusters of 4 outputs.
__global__ __launch_bounds__(512) void k_soft(const float* __restrict__ x,
                                              float* __restrict__ ws) {
    const int tid = threadIdx.x;
    const int bq = blockIdx.x;
    const int w = tid >> 6, l = tid & 63;
    __shared__ float red[16];
    char* row = (char*)ws + S_OFF + (size_t)bq * RSB;
    const float* xrow = x + (size_t)bq * L_;
    const float* kc = ws + 65;                 // uniform -> s_load

    // zero the row pads (left 512 B, right 512 B)
    const uint4 z4 = {0u, 0u, 0u, 0u};
    if (tid < 32) *(uint4*)(row + 16 * tid) = z4;
    else if (tid >= 64 && tid < 96) *(uint4*)(row + 16896 + 16 * (tid - 64)) = z4;

    float y[16];
    #pragma unroll
    for (int jc = 0; jc < 4; jc++) {
        const int Wb = 1024 * w + 256 * jc + 4 * l - 28;   // window base (float idx)
        float vv[64];
        #pragma unroll
        for (int i = 0; i < 16; i++) {
            const int f = Wb + 4 * i;
            float4 t4;
            if (f >= 0 && f + 4 <= L_) {
                t4 = *(const float4*)(xrow + f);
            } else {
                t4.x = (f + 0 >= 0 && f + 0 < L_) ? xrow[f + 0] : 0.0f;
                t4.y = (f + 1 >= 0 && f + 1 < L_) ? xrow[f + 1] : 0.0f;
                t4.z = (f + 2 >= 0 && f + 2 < L_) ? xrow[f + 2] : 0.0f;
                t4.w = (f + 3 >= 0 && f + 3 < L_) ? xrow[f + 3] : 0.0f;
            }
            vv[4 * i + 0] = t4.x; vv[4 * i + 1] = t4.y;
            vv[4 * i + 2] = t4.z; vv[4 * i + 3] = t4.w;
        }
        #pragma unroll
        for (int e = 0; e < 4; e++) {
            float a = 0.0f;
            #pragma unroll
            for (int m = 0; m < KCONV; m++) a = fmaf(vv[e + m + 3], kc[m], a);
            y[4 * jc + e] = a;
        }
    }
    // block max
    float mx = -3.402823466e+38f;
    #pragma unroll
    for (int i = 0; i < 16; i++) mx = fmaxf(mx, y[i]);
    #pragma unroll
    for (int o = 32; o > 0; o >>= 1) mx = fmaxf(mx, __shfl_xor(mx, o));
    if (l == 0) red[w] = mx;
    __syncthreads();
    mx = red[0];
    #pragma unroll
    for (int i = 1; i < 8; i++) mx = fmaxf(mx, red[i]);
    // single exp pass + block sum
    float sm = 0.0f;
    #pragma unroll
    for (int i = 0; i < 16; i++) { y[i] = __expf(y[i] - mx); sm += y[i]; }
    #pragma unroll
    for (int o = 32; o > 0; o >>= 1) sm += __shfl_xor(sm, o);
    if (l == 0) red[8 + w] = sm;
    __syncthreads();
    float s = red[8];
    #pragma unroll
    for (int i = 1; i < 8; i++) s += red[8 + i];
    const float isum = 1.0f / s;
    // store 16 f16 values as 4 coalesced 8-B stores
    union PK { _Float16 h[4]; uint2 u; };
    #pragma unroll
    for (int jc = 0; jc < 4; jc++) {
        PK pk;
        #pragma unroll
        for (int e = 0; e < 4; e++) pk.h[e] = (_Float16)(y[4 * jc + e] * isum);
        *(uint2*)(row + 512 + 2 * (1024 * w + 256 * jc + 4 * l)) = pk.u;
    }
}

// ---------------- kernel 3: 32x32x16 MFMA banded-Toeplitz conv501 + lattice ----------------
// 128 threads = 2 waves; each wave owns one (b, 1024-l tile) job: barrier-free,
// private double-buffered swizzled LDS, reg-staged prefetch of next q under MFMA.
__global__ __launch_bounds__(128) void k_conv(const float* __restrict__ ws,
                                              float* __restrict__ out) {
    const int tid = threadIdx.x;
    const int wv = tid >> 6, lane = tid & 63;
    const int j = lane & 31, hi = lane >> 5;
    const int b = blockIdx.y;
    const int t = blockIdx.x * 2 + wv;
    const char* wsb = (const char*)ws;
    __shared__ __attribute__((aligned(128))) char sbuf[2][2][3072];
    char* buf0 = sbuf[wv][0];
    char* buf1 = sbuf[wv][1];

    // swizzled LDS read offsets per chunk (q-invariant): linear = 64j + 32c + 16hi
    int bofs[NCH2];
    #pragma unroll
    for (int c = 0; c < NCH2; c++) bofs[c] = SWZ(64 * j + 32 * c + 16 * hi);
    // swizzled LDS write offsets (3 slots per lane: l, l+64, l+128)
    int wofs[3];
    #pragma unroll
    for (int k = 0; k < 3; k++) wofs[k] = SWZ(16 * (lane + 64 * k));

    const char* gsrc = wsb + S_OFF + (size_t)(b * Q_) * RSB + 2048 * t;
    const float inv_scale = ws[64];

    float r[16], t2[16];
    #pragma unroll
    for (int e = 0; e < 16; e++) { r[e] = 0.0f; t2[e] = 1.0f; }

    // prologue: stage q=0 into buf0
    uint4 s0 = *(const uint4*)(gsrc + 16 * lane);
    uint4 s1 = *(const uint4*)(gsrc + 16 * (lane + 64));
    uint4 s2 = *(const uint4*)(gsrc + 16 * (lane + 128));
    *(uint4*)(buf0 + wofs[0]) = s0;
    *(uint4*)(buf0 + wofs[1]) = s1;
    *(uint4*)(buf0 + wofs[2]) = s2;

    int cur = 0;
    for (int q = 0; q < Q_; q++) {
        if (q < Q_ - 1) {                       // issue next-q loads early (hide under MFMA)
            const char* g = gsrc + (size_t)(q + 1) * RSB;
            s0 = *(const uint4*)(g + 16 * lane);
            s1 = *(const uint4*)(g + 16 * (lane + 64));
            s2 = *(const uint4*)(g + 16 * (lane + 128));
        }
        const char* bb = cur ? buf1 : buf0;
        const char* tab = wsb + TA_OFF + ((size_t)q * (NCH2 * 64) + lane) * 16;
        f32x16 acc = {};
        #pragma unroll
        for (int c = 0; c < NCH2; c++) {
            f16x8 af = *(const f16x8*)(tab + c * 1024);     // Toeplitz kernel frag (L2-hot)
            f16x8 bf = *(const f16x8*)(bb + bofs[c]);       // data frag (swizzled ds_read_b128)
            acc = __builtin_amdgcn_mfma_f32_32x32x16_f16(af, bf, acc, 0, 0, 0);
        }
        const float aq = ws[q];
        #pragma unroll
        for (int e = 0; e < 16; e++) {
            float rn = acc[e], tn = 1.0f - rn;
            float si = 1.0f / (1.0f - aq * r[e] * rn);
            float rnew = r[e] + aq * rn * t2[e] * si;
            t2[e] = aq * t2[e] * tn * tn * si * si;
            r[e] = rnew;
        }
        if (q < Q_ - 1) {
            char* wb = cur ? buf0 : buf1;
            *(uint4*)(wb + wofs[0]) = s0;
            *(uint4*)(wb + wofs[1]) = s1;
            *(uint4*)(wb + wofs[2]) = s2;
            cur ^= 1;
        }
    }
    // D layout: col = lane&31 (=j), row = (reg&3) + 8*(reg>>2) + 4*(lane>>5)
    #pragma unroll
    for (int e = 0; e < 16; e++) {
        const int rrow = (e & 3) + 8 * (e >> 2) + 4 * hi;
        out[(size_t)b * L_ + 1024 * t + 32 * j + rrow] = r[e] * inv_scale;
    }
}

extern "C" void kernel_launch(void* const* d_in, const int* in_sizes, int n_in,
                              void* d_out, int out_size, void* d_ws, size_t ws_size,
                              hipStream_t stream) {
    (void)in_sizes; (void)n_in; (void)out_size; (void)ws_size;
    const float* x    = (const float*)d_in[0];
    const float* cwh  = (const float*)d_in[1];
    const float* tcw  = (const float*)d_in[2];
    const float* araw = (const float*)d_in[3];
    float* out = (float*)d_out;
    float* ws  = (float*)d_ws;

    hipLaunchKernelGGL(k_params, dim3(Q_ + 1), dim3(256), 0, stream, cwh, tcw, araw, ws);
    hipLaunchKernelGGL(k_soft, dim3(B_ * Q_), dim3(512), 0, stream, x, ws);
    hipLaunchKernelGGL(k_conv, dim3(4, B_), dim3(128), 0, stream, ws, out);
}

// Round 6
// 137.080 us; speedup vs baseline: 9.1879x; 9.1879x over previous
//
#include <hip/hip_runtime.h>

#define B_ 64
#define Q_ 64
#define L_ 8192
#define KCONV 51
#define HC 26
#define HT 251
#define NCH2 34               // K-chunks of 16 covering taps (with -6 shift)

// ---- workspace layout (bytes), total 69,337,600 <= proven-safe 73.5 MB ----
#define TA_OFF 512            // PAR: a[64] floats @0, scale @64
#define RN_OFF 2228736        // 512 + 64*34*64*16 ; rn f16 [B][Q][L] = 67,108,864 B

// exact-balance LDS slot permutation (slot = 16B unit):
// pi(s) = (s & ~7) | (((s&7) + (s>>3)) & 7); returns BYTE offset.
// Bijective within each 8-slot group; applied identically on write and read.
#define MAPB(s) ((((s) & ~7) | ((((s) & 7) + ((s) >> 3)) & 7)) << 4)

typedef _Float16 f16x8 __attribute__((ext_vector_type(8)));
typedef float f32x16 __attribute__((ext_vector_type(16)));

__device__ __forceinline__ float sigm(float v) {
    return 1.0f / (1.0f + __expf(-v));
}

// ---------------- kernel 1: A-table (Toeplitz kernel fragments) + a/scale ----------------
__global__ __launch_bounds__(256) void k_params(const float* __restrict__ tcw,
                                                const float* __restrict__ araw,
                                                float* __restrict__ ws) {
    const int tid = threadIdx.x;
    const int q = blockIdx.x;
    char* wsb = (char*)ws;
    if (q < Q_) {
        // TA[q][c][lane] = 8 halves: A_c[i=lane&31, kappa=8*(lane>>5)+jj]
        //                = kt_q[16c + 8*(lane>>5) + jj - (lane&31) - 6]
        for (int idx = tid; idx < NCH2 * 64; idx += 256) {
            int c = idx >> 6, lane = idx & 63;
            int hi = lane >> 5, i = lane & 31;
            int mbase = 16 * c + 8 * hi - i - 6;
            f16x8 hv;
            #pragma unroll
            for (int jj = 0; jj < 8; jj++) {
                int m = mbase + jj;
                float v = 0.0f;
                if (m >= 0 && m <= 500) {
                    int hh = (m <= 250) ? m : (500 - m);
                    v = sigm(tcw[q * HT + hh]);
                }
                hv[jj] = (_Float16)v;
            }
            *(f16x8*)(wsb + TA_OFF + ((size_t)q * (NCH2 * 64) + idx) * 16) = hv;
        }
    } else {
        if (tid < Q_) ws[tid] = sigm(araw[tid]);
        __syncthreads();
        if (tid == 0) {
            float p = 1.0f;
            for (int j = 0; j < Q_; j++) p *= ws[j];
            float peak = sigm(tcw[(Q_ - 1) * HT + 250]);
            ws[64] = 1.0f / (peak * p);
        }
    }
}

// ---------------- kernel 2: conv51 + softmax (LDS) + MFMA conv501 -> rn ----------------
// one block per (b,q) row; 512 threads = 8 waves; S never touches HBM.
__global__ __launch_bounds__(512, 1) void k_fused(const float* __restrict__ x,
                                                  const float* __restrict__ cwh,
                                                  float* __restrict__ ws) {
    const int tid = threadIdx.x;
    const int bid = blockIdx.x;           // = b*64 + q
    const int q = bid & 63;
    char* wsb = (char*)ws;
    __shared__ __attribute__((aligned(128))) char sm[17408];  // 1088 16B slots
    __shared__ float red[16];

    // ---- phase 1: conv51 + softmax into LDS (f16, pi-permuted, halo-padded) ----
    if (tid < 64) {                        // zero halo slots (l in [-256,0) u [8192,8448))
        int slot = (tid < 32) ? tid : (1024 + tid);
        const uint4 z4 = {0u, 0u, 0u, 0u};
        *(uint4*)(sm + MAPB(slot)) = z4;
    }
    const float* xrow = x + (size_t)bid * L_;
    // window: outputs l = 16*tid + e, e in [0,16) need x[L0-25 .. L0+40]
    // vv[idx] = x[L0 - 28 + idx]; need idx 3..68 -> fill 18 float4 (idx 0..71)
    float vv[72];
    const int L0 = 16 * tid;
    #pragma unroll
    for (int i = 0; i < 18; i++) {
        const int f = L0 - 28 + 4 * i;
        float4 t4;
        if (f >= 0 && f + 4 <= L_) {
            t4 = *(const float4*)(xrow + f);
        } else {
            t4.x = (f + 0 >= 0 && f + 0 < L_) ? xrow[f + 0] : 0.0f;
            t4.y = (f + 1 >= 0 && f + 1 < L_) ? xrow[f + 1] : 0.0f;
            t4.z = (f + 2 >= 0 && f + 2 < L_) ? xrow[f + 2] : 0.0f;
            t4.w = (f + 3 >= 0 && f + 3 < L_) ? xrow[f + 3] : 0.0f;
        }
        vv[4 * i + 0] = t4.x; vv[4 * i + 1] = t4.y;
        vv[4 * i + 2] = t4.z; vv[4 * i + 3] = t4.w;
    }
    float y[16];
    #pragma unroll
    for (int e = 0; e < 16; e++) {
        float a = 0.0f;
        #pragma unroll
        for (int m = 0; m < KCONV; m++)
            a = fmaf(vv[e + 3 + m], cwh[m < HC ? m : (KCONV - 1 - m)], a); // s_loads
        y[e] = a;
    }
    const int w = tid >> 6, l = tid & 63;
    float mx = -3.402823466e+38f;
    #pragma unroll
    for (int i = 0; i < 16; i++) mx = fmaxf(mx, y[i]);
    #pragma unroll
    for (int o = 32; o > 0; o >>= 1) mx = fmaxf(mx, __shfl_xor(mx, o));
    if (l == 0) red[w] = mx;
    __syncthreads();
    mx = red[0];
    #pragma unroll
    for (int i = 1; i < 8; i++) mx = fmaxf(mx, red[i]);
    float sm_ = 0.0f;
    #pragma unroll
    for (int i = 0; i < 16; i++) { y[i] = __expf(y[i] - mx); sm_ += y[i]; }
    #pragma unroll
    for (int o = 32; o > 0; o >>= 1) sm_ += __shfl_xor(sm_, o);
    if (l == 0) red[8 + w] = sm_;
    __syncthreads();
    float ssum = red[8];
    #pragma unroll
    for (int i = 1; i < 8; i++) ssum += red[8 + i];
    const float isum = 1.0f / ssum;
    union PK { _Float16 h[8]; uint4 u; };
    {
        PK p0, p1;
        #pragma unroll
        for (int e = 0; e < 8; e++) {
            p0.h[e] = (_Float16)(y[e] * isum);
            p1.h[e] = (_Float16)(y[8 + e] * isum);
        }
        *(uint4*)(sm + MAPB(32 + 2 * tid)) = p0.u;   // halves H=256+16t (H = l+256)
        *(uint4*)(sm + MAPB(33 + 2 * tid)) = p1.u;
    }
    __syncthreads();

    // ---- phase 2: 34x mfma_f32_32x32x16_f16; wave w owns tile l in [1024w,1024w+1024) ----
    const int lane = tid & 63, j = lane & 31, hi = lane >> 5;
    int bofs[NCH2];
    #pragma unroll
    for (int c = 0; c < NCH2; c++) bofs[c] = MAPB(128 * w + 4 * j + 2 * c + hi);
    const char* tab = wsb + TA_OFF + ((size_t)q * (NCH2 * 64) + lane) * 16;
    f32x16 acc = {};
    #pragma unroll
    for (int c = 0; c < NCH2; c++) {
        f16x8 af = *(const f16x8*)(tab + c * 1024);   // A frags: L2-broadcast across b
        f16x8 bf = *(const f16x8*)(sm + bofs[c]);     // conflict-free ds_read_b128
        acc = __builtin_amdgcn_mfma_f32_32x32x16_f16(af, bf, acc, 0, 0, 0);
    }
    __syncthreads();                                  // all phase-2 reads done

    // ---- phase 3a: transpose D to l-linear via LDS (b64 writes) ----
    // value e at l = 1024w + 32j + (e&3) + 8*(e>>2) + 4*hi
    union P4 { _Float16 h[4]; uint2 u; };
    #pragma unroll
    for (int k = 0; k < 4; k++) {
        P4 p;
        #pragma unroll
        for (int d = 0; d < 4; d++) p.h[d] = (_Float16)acc[4 * k + d];
        *(uint2*)(sm + MAPB(128 * w + 4 * j + k) + 8 * hi) = p.u;
    }
    __syncthreads();

    // ---- phase 3b: coalesced rn store (32B/thread) ----
    uint4 r0 = *(uint4*)(sm + MAPB(2 * tid));
    uint4 r1 = *(uint4*)(sm + MAPB(2 * tid + 1));
    char* dst = wsb + RN_OFF + ((size_t)bid * L_ + 16 * tid) * 2;
    *(uint4*)dst = r0;
    *(uint4*)(dst + 16) = r1;
}

// ---------------- kernel 3: serial-q lattice on rn (exact reference scan) ----------------
__global__ __launch_bounds__(256) void k_lat(const float* __restrict__ ws,
                                             float* __restrict__ out) {
    const int tid = threadIdx.x;
    const int T = blockIdx.x & 7, b = blockIdx.x >> 3;
    const char* wsb = (const char*)ws;
    const int l = 1024 * T + 4 * tid;
    const char* src = wsb + RN_OFF + ((size_t)(b * Q_) * L_ + l) * 2;
    float r[4] = {0.0f, 0.0f, 0.0f, 0.0f};
    float t2[4] = {1.0f, 1.0f, 1.0f, 1.0f};
    union P4 { _Float16 h[4]; uint2 u; };
    P4 cur;
    cur.u = *(const uint2*)src;
    for (int q = 0; q < Q_; q++) {
        P4 nxt = cur;
        if (q < Q_ - 1) nxt.u = *(const uint2*)(src + (size_t)(q + 1) * L_ * 2);
        const float aq = ws[q];
        #pragma unroll
        for (int e = 0; e < 4; e++) {
            float rn = (float)cur.h[e], tn = 1.0f - rn;
            float si = 1.0f / (1.0f - aq * r[e] * rn);
            float rnew = r[e] + aq * rn * t2[e] * si;
            t2[e] = aq * t2[e] * tn * tn * si * si;
            r[e] = rnew;
        }
        cur = nxt;
    }
    const float inv_scale = ws[64];
    float4 o;
    o.x = r[0] * inv_scale; o.y = r[1] * inv_scale;
    o.z = r[2] * inv_scale; o.w = r[3] * inv_scale;
    *(float4*)&out[(size_t)b * L_ + l] = o;
}

extern "C" void kernel_launch(void* const* d_in, const int* in_sizes, int n_in,
                              void* d_out, int out_size, void* d_ws, size_t ws_size,
                              hipStream_t stream) {
    (void)in_sizes; (void)n_in; (void)out_size; (void)ws_size;
    const float* x    = (const float*)d_in[0];
    const float* cwh  = (const float*)d_in[1];
    const float* tcw  = (const float*)d_in[2];
    const float* araw = (const float*)d_in[3];
    float* out = (float*)d_out;
    float* ws  = (float*)d_ws;

    hipLaunchKernelGGL(k_params, dim3(Q_ + 1), dim3(256), 0, stream, tcw, araw, ws);
    hipLaunchKernelGGL(k_fused, dim3(B_ * Q_), dim3(512), 0, stream, x, cwh, ws);
    hipLaunchKernelGGL(k_lat, dim3(B_ * 8), dim3(256), 0, stream, ws, out);
}

// Round 7
// 102.627 us; speedup vs baseline: 12.2724x; 1.3357x over previous
//
#include <hip/hip_runtime.h>

#define B_ 64
#define Q_ 64
#define L_ 8192
#define KCONV 51
#define HC 26
#define HT 251
#define NCH2 34               // conv501 K-chunks of 16 (shift -6)
#define NCH1 6                // conv51  K-chunks of 16 (shift -7)

// ---- workspace layout (bytes), total 69,345,280 <= proven-safe 73.5 MB ----
// PAR floats: a[0..63] @0, scale @64
#define A51_OFF 512           // 6*64*16 = 6144 B
#define TA_OFF  8192          // 64*34*64*16 = 2,228,224 B
#define RN_OFF  2236416       // rn f16 [B][Q][L] = 67,108,864 B

// exact-balance LDS slot permutation (slot = 16B unit), bijective per 8-slot
// group; applied identically on every write and read.
#define MAPB(s) ((((s) & ~7) | ((((s) & 7) + ((s) >> 3)) & 7)) << 4)

typedef _Float16 f16x8 __attribute__((ext_vector_type(8)));
typedef float f32x16 __attribute__((ext_vector_type(16)));

__device__ __forceinline__ float sigm(float v) {
    return 1.0f / (1.0f + __expf(-v));
}

// ---------------- kernel 1: A-tables (Toeplitz fragments) + a/scale ----------------
__global__ __launch_bounds__(256) void k_params(const float* __restrict__ cwh,
                                                const float* __restrict__ tcw,
                                                const float* __restrict__ araw,
                                                float* __restrict__ ws) {
    const int tid = threadIdx.x;
    const int q = blockIdx.x;
    char* wsb = (char*)ws;
    if (q < Q_) {
        // TA[q][c][lane]: A_c[i=lane&31, kappa=8*(lane>>5)+jj] = kt_q[16c+8hi+jj-i-6]
        for (int idx = tid; idx < NCH2 * 64; idx += 256) {
            int c = idx >> 6, lane = idx & 63;
            int hi = lane >> 5, i = lane & 31;
            int mbase = 16 * c + 8 * hi - i - 6;
            f16x8 hv;
            #pragma unroll
            for (int jj = 0; jj < 8; jj++) {
                int m = mbase + jj;
                float v = 0.0f;
                if (m >= 0 && m <= 500) {
                    int hh = (m <= 250) ? m : (500 - m);
                    v = sigm(tcw[q * HT + hh]);
                }
                hv[jj] = (_Float16)v;
            }
            *(f16x8*)(wsb + TA_OFF + ((size_t)q * (NCH2 * 64) + idx) * 16) = hv;
        }
    } else {
        if (tid < Q_) ws[tid] = sigm(araw[tid]);
        // A51[c][lane]: A_c[i,kappa] = kc[16c+8hi+jj-i-7], kc[m]=cwh[min(m,50-m)]
        for (int idx = tid; idx < NCH1 * 64; idx += 256) {
            int c = idx >> 6, lane = idx & 63;
            int hi = lane >> 5, i = lane & 31;
            int mbase = 16 * c + 8 * hi - i - 7;
            f16x8 hv;
            #pragma unroll
            for (int jj = 0; jj < 8; jj++) {
                int m = mbase + jj;
                float v = 0.0f;
                if (m >= 0 && m < KCONV) v = cwh[m < HC ? m : (KCONV - 1 - m)];
                hv[jj] = (_Float16)v;
            }
            *(f16x8*)(wsb + A51_OFF + idx * 16) = hv;
        }
        __syncthreads();
        if (tid == 0) {
            float p = 1.0f;
            for (int j = 0; j < Q_; j++) p *= ws[j];
            float peak = sigm(tcw[(Q_ - 1) * HT + 250]);
            ws[64] = 1.0f / (peak * p);
        }
    }
}

// ---------------- kernel 2: all-MFMA conv51 -> softmax -> conv501 -> rn ----------------
// one block per (b,q) row; 512 threads = 8 waves; wave w owns l in [1024w,1024w+1024).
// grid mapped q-major so co-resident blocks share TA[q] (L1/L2 locality).
__global__ __launch_bounds__(512, 2) void k_fused(const float* __restrict__ x,
                                                  float* __restrict__ ws) {
    const int tid = threadIdx.x;
    const int bid = blockIdx.x;
    const int q = bid >> 6, b = bid & 63;
    const int row = b * Q_ + q;                 // x / rn row
    char* wsb = (char*)ws;
    __shared__ __attribute__((aligned(128))) char xb[16512];  // 1032 slots: x f16, halo 32
    __shared__ __attribute__((aligned(128))) char sb[17408];  // 1088 slots: S f16, halo 256
    __shared__ float red[16];

    const int w = tid >> 6, lane = tid & 63, j = lane & 31, hi = lane >> 5;

    // conv51 A-fragments -> 24 VGPRs (shared across all q; L1-hot)
    f16x8 a51[NCH1];
    #pragma unroll
    for (int c = 0; c < NCH1; c++)
        a51[c] = *(const f16x8*)(wsb + A51_OFF + (c * 64 + lane) * 16);

    // B-fragment LDS offsets (identical formula for both convs/buffers)
    int bofs[NCH2];
    #pragma unroll
    for (int c = 0; c < NCH2; c++) bofs[c] = MAPB(128 * w + 4 * j + 2 * c + hi);

    // zero halos: xb slots {0..3, 1028..1031}; sb slots {0..31, 1056..1087}
    const uint4 z4 = {0u, 0u, 0u, 0u};
    if (tid < 8) { int s = (tid < 4) ? tid : 1024 + tid; *(uint4*)(xb + MAPB(s)) = z4; }
    if (tid >= 32 && tid < 96) {
        int s = (tid < 64) ? (tid - 32) : (1056 + tid - 64);
        *(uint4*)(sb + MAPB(s)) = z4;
    }

    // stage x row as f16: thread t covers halves H = 16t+32 .. +16 (slots 2t+4, 2t+5)
    {
        const float* xrow = x + (size_t)row * L_;
        float4 f0 = *(const float4*)(xrow + 16 * tid);
        float4 f1 = *(const float4*)(xrow + 16 * tid + 4);
        float4 f2 = *(const float4*)(xrow + 16 * tid + 8);
        float4 f3 = *(const float4*)(xrow + 16 * tid + 12);
        union H8 { _Float16 h[8]; uint4 u; } h0, h1;
        h0.h[0] = (_Float16)f0.x; h0.h[1] = (_Float16)f0.y;
        h0.h[2] = (_Float16)f0.z; h0.h[3] = (_Float16)f0.w;
        h0.h[4] = (_Float16)f1.x; h0.h[5] = (_Float16)f1.y;
        h0.h[6] = (_Float16)f1.z; h0.h[7] = (_Float16)f1.w;
        h1.h[0] = (_Float16)f2.x; h1.h[1] = (_Float16)f2.y;
        h1.h[2] = (_Float16)f2.z; h1.h[3] = (_Float16)f2.w;
        h1.h[4] = (_Float16)f3.x; h1.h[5] = (_Float16)f3.y;
        h1.h[6] = (_Float16)f3.z; h1.h[7] = (_Float16)f3.w;
        *(uint4*)(xb + MAPB(2 * tid + 4)) = h0.u;
        *(uint4*)(xb + MAPB(2 * tid + 5)) = h1.u;
    }
    __syncthreads();                                          // S1: stage done

    // ---- conv51 via 6 MFMAs ----
    f32x16 acc = {};
    #pragma unroll
    for (int c = 0; c < NCH1; c++) {
        f16x8 bf = *(const f16x8*)(xb + bofs[c]);
        acc = __builtin_amdgcn_mfma_f32_32x32x16_f16(a51[c], bf, acc, 0, 0, 0);
    }

    // ---- softmax over the 8192 accs held by the block ----
    float mx = -3.402823466e+38f;
    #pragma unroll
    for (int e = 0; e < 16; e++) mx = fmaxf(mx, acc[e]);
    #pragma unroll
    for (int o = 32; o > 0; o >>= 1) mx = fmaxf(mx, __shfl_xor(mx, o));
    if (lane == 0) red[w] = mx;
    __syncthreads();                                          // S2
    mx = red[0];
    #pragma unroll
    for (int i = 1; i < 8; i++) mx = fmaxf(mx, red[i]);
    float sm = 0.0f;
    #pragma unroll
    for (int e = 0; e < 16; e++) { acc[e] = __expf(acc[e] - mx); sm += acc[e]; }
    #pragma unroll
    for (int o = 32; o > 0; o >>= 1) sm += __shfl_xor(sm, o);
    if (lane == 0) red[8 + w] = sm;
    __syncthreads();                                          // S3
    float ssum = red[8];
    #pragma unroll
    for (int i = 1; i < 8; i++) ssum += red[8 + i];
    const float isum = 1.0f / ssum;

    // write S (f16) into sb via D-layout transpose: e=4k+d -> l = 1024w+32j+8k+4hi+d
    union P4 { _Float16 h[4]; uint2 u; };
    #pragma unroll
    for (int k = 0; k < 4; k++) {
        P4 p;
        #pragma unroll
        for (int d = 0; d < 4; d++) p.h[d] = (_Float16)(acc[4 * k + d] * isum);
        *(uint2*)(sb + MAPB(128 * w + 4 * j + k + 32) + 8 * hi) = p.u;
    }
    __syncthreads();                                          // S4: S ready

    // ---- conv501 via 34 MFMAs (A frags from L2-hot TA[q]) ----
    const char* tab = wsb + TA_OFF + ((size_t)q * (NCH2 * 64) + lane) * 16;
    f32x16 acc2 = {};
    #pragma unroll
    for (int c = 0; c < NCH2; c++) {
        f16x8 af = *(const f16x8*)(tab + c * 1024);
        f16x8 bf = *(const f16x8*)(sb + bofs[c]);
        acc2 = __builtin_amdgcn_mfma_f32_32x32x16_f16(af, bf, acc2, 0, 0, 0);
    }

    // ---- transpose to l-linear via xb (free after S2), then coalesced store ----
    #pragma unroll
    for (int k = 0; k < 4; k++) {
        P4 p;
        #pragma unroll
        for (int d = 0; d < 4; d++) p.h[d] = (_Float16)acc2[4 * k + d];
        *(uint2*)(xb + MAPB(128 * w + 4 * j + k) + 8 * hi) = p.u;
    }
    __syncthreads();                                          // S5
    uint4 r0 = *(uint4*)(xb + MAPB(2 * tid));
    uint4 r1 = *(uint4*)(xb + MAPB(2 * tid + 1));
    char* dst = wsb + RN_OFF + ((size_t)row * L_ + 16 * tid) * 2;
    *(uint4*)dst = r0;
    *(uint4*)(dst + 16) = r1;
}

// ---------------- kernel 3: serial-q lattice on rn (exact reference scan) ----------------
__global__ __launch_bounds__(256) void k_lat(const float* __restrict__ ws,
                                             float* __restrict__ out) {
    const int tid = threadIdx.x;
    const int T = blockIdx.x & 7, b = blockIdx.x >> 3;
    const char* wsb = (const char*)ws;
    const int l = 1024 * T + 4 * tid;
    const char* src = wsb + RN_OFF + ((size_t)(b * Q_) * L_ + l) * 2;
    float r[4] = {0.0f, 0.0f, 0.0f, 0.0f};
    float t2[4] = {1.0f, 1.0f, 1.0f, 1.0f};
    union P4 { _Float16 h[4]; uint2 u; };
    P4 cur;
    cur.u = *(const uint2*)src;
    for (int q = 0; q < Q_; q++) {
        P4 nxt = cur;
        if (q < Q_ - 1) nxt.u = *(const uint2*)(src + (size_t)(q + 1) * L_ * 2);
        const float aq = ws[q];
        #pragma unroll
        for (int e = 0; e < 4; e++) {
            float rn = (float)cur.h[e], tn = 1.0f - rn;
            float si = 1.0f / (1.0f - aq * r[e] * rn);
            float rnew = r[e] + aq * rn * t2[e] * si;
            t2[e] = aq * t2[e] * tn * tn * si * si;
            r[e] = rnew;
        }
        cur = nxt;
    }
    const float inv_scale = ws[64];
    float4 o;
    o.x = r[0] * inv_scale; o.y = r[1] * inv_scale;
    o.z = r[2] * inv_scale; o.w = r[3] * inv_scale;
    *(float4*)&out[(size_t)b * L_ + l] = o;
}

extern "C" void kernel_launch(void* const* d_in, const int* in_sizes, int n_in,
                              void* d_out, int out_size, void* d_ws, size_t ws_size,
                              hipStream_t stream) {
    (void)in_sizes; (void)n_in; (void)out_size; (void)ws_size;
    const float* x    = (const float*)d_in[0];
    const float* cwh  = (const float*)d_in[1];
    const float* tcw  = (const float*)d_in[2];
    const float* araw = (const float*)d_in[3];
    float* out = (float*)d_out;
    float* ws  = (float*)d_ws;

    hipLaunchKernelGGL(k_params, dim3(Q_ + 1), dim3(256), 0, stream, cwh, tcw, araw, ws);
    hipLaunchKernelGGL(k_fused, dim3(B_ * Q_), dim3(512), 0, stream, x, ws);
    hipLaunchKernelGGL(k_lat, dim3(B_ * 8), dim3(256), 0, stream, ws, out);
}

// Round 8
// 97.854 us; speedup vs baseline: 12.8710x; 1.0488x over previous
//
#include <hip/hip_runtime.h>

#define B_ 64
#define Q_ 64
#define L_ 8192
#define KCONV 51
#define HC 26
#define HT 251
#define NCH2 34               // conv501 K-chunks of 16 (shift -6)
#define NCH1 6                // conv51  K-chunks of 16 (shift -7)
#define TAL_CH 28             // conv501 chunks staged in LDS (rest from L2)

// ---- workspace layout (bytes), total 69,345,280 <= proven-safe 73.5 MB ----
// PAR floats: a[0..63] @0, scale @64
#define A51_OFF 512           // 6*64*16 = 6144 B
#define TA_OFF  8192          // 64*34*64*16 = 2,228,224 B
#define RN_OFF  2236416       // rn f16 [B][Q][L] = 67,108,864 B

// exact-balance LDS slot permutation (slot = 16B unit), bijective per 8-slot
// group; applied identically on every write and read.
#define MAPB(s) ((((s) & ~7) | ((((s) & 7) + ((s) >> 3)) & 7)) << 4)

typedef _Float16 f16x8 __attribute__((ext_vector_type(8)));
typedef float f32x16 __attribute__((ext_vector_type(16)));
typedef const __attribute__((address_space(1))) void cg_void;
typedef __attribute__((address_space(3))) void lds_void3;

__device__ __forceinline__ float sigm(float v) {
    return 1.0f / (1.0f + __expf(-v));
}

// ---------------- kernel 1: A-tables (Toeplitz fragments) + a/scale ----------------
__global__ __launch_bounds__(256) void k_params(const float* __restrict__ cwh,
                                                const float* __restrict__ tcw,
                                                const float* __restrict__ araw,
                                                float* __restrict__ ws) {
    const int tid = threadIdx.x;
    const int q = blockIdx.x;
    char* wsb = (char*)ws;
    if (q < Q_) {
        // TA[q][c][lane]: A_c[i=lane&31, kappa=8*(lane>>5)+jj] = kt_q[16c+8hi+jj-i-6]
        for (int idx = tid; idx < NCH2 * 64; idx += 256) {
            int c = idx >> 6, lane = idx & 63;
            int hi = lane >> 5, i = lane & 31;
            int mbase = 16 * c + 8 * hi - i - 6;
            f16x8 hv;
            #pragma unroll
            for (int jj = 0; jj < 8; jj++) {
                int m = mbase + jj;
                float v = 0.0f;
                if (m >= 0 && m <= 500) {
                    int hh = (m <= 250) ? m : (500 - m);
                    v = sigm(tcw[q * HT + hh]);
                }
                hv[jj] = (_Float16)v;
            }
            *(f16x8*)(wsb + TA_OFF + ((size_t)q * (NCH2 * 64) + idx) * 16) = hv;
        }
    } else {
        if (tid < Q_) ws[tid] = sigm(araw[tid]);
        // A51[c][lane]: A_c[i,kappa] = kc[16c+8hi+jj-i-7], kc[m]=cwh[min(m,50-m)]
        for (int idx = tid; idx < NCH1 * 64; idx += 256) {
            int c = idx >> 6, lane = idx & 63;
            int hi = lane >> 5, i = lane & 31;
            int mbase = 16 * c + 8 * hi - i - 7;
            f16x8 hv;
            #pragma unroll
            for (int jj = 0; jj < 8; jj++) {
                int m = mbase + jj;
                float v = 0.0f;
                if (m >= 0 && m < KCONV) v = cwh[m < HC ? m : (KCONV - 1 - m)];
                hv[jj] = (_Float16)v;
            }
            *(f16x8*)(wsb + A51_OFF + idx * 16) = hv;
        }
        __syncthreads();
        if (tid == 0) {
            float p = 1.0f;
            for (int j = 0; j < Q_; j++) p *= ws[j];
            float peak = sigm(tcw[(Q_ - 1) * HT + 250]);
            ws[64] = 1.0f / (peak * p);
        }
    }
}

// ---------------- kernel 2: paired-row all-MFMA conv51 -> softmax -> conv501 ----------
// block = (q, b-pair); 512 threads = 8 waves; wave w owns l-tile [1024w,1024w+1024)
// for BOTH rows. One 17.4 KB buffer per row holds x, then S, then the output.
// TA[q] (28/34 chunks) async-staged to LDS; each A-frag feeds 2 MFMAs.
__global__ __launch_bounds__(512, 4) void k_fused(const float* __restrict__ x,
                                                  float* __restrict__ ws) {
    const int tid = threadIdx.x;
    const int bid = blockIdx.x;
    const int q = bid >> 5, pr = bid & 31;
    const int row0 = (2 * pr) * Q_ + q, row1 = (2 * pr + 1) * Q_ + q;
    char* wsb = (char*)ws;
    __shared__ __attribute__((aligned(128))) char bufA[17408];  // 1088 slots
    __shared__ __attribute__((aligned(128))) char bufB[17408];
    __shared__ __attribute__((aligned(128))) char TAL[TAL_CH * 1024];
    __shared__ float red[32];

    const int w = tid >> 6, lane = tid & 63, j = lane & 31, hi = lane >> 5;

    // ---- issue async TA[q] -> LDS staging first (overlaps x HBM loads) ----
    {
        const char* tabg = wsb + TA_OFF + (size_t)q * (NCH2 * 64) * 16;
        for (int c = w; c < TAL_CH; c += 8) {
            const void* gp = tabg + (c * 64 + lane) * 16;
            __builtin_amdgcn_global_load_lds((cg_void*)gp,
                                             (lds_void3*)(TAL + c * 1024), 16, 0, 0);
        }
    }

    // ---- zero halos (slots 0..31 and 1056..1087 of both buffers) ----
    const uint4 z4 = {0u, 0u, 0u, 0u};
    if (tid < 32) {
        *(uint4*)(bufA + MAPB(tid)) = z4;
        *(uint4*)(bufB + MAPB(tid)) = z4;
    } else if (tid >= 64 && tid < 96) {
        int s = 1056 + (tid - 64);
        *(uint4*)(bufA + MAPB(s)) = z4;
        *(uint4*)(bufB + MAPB(s)) = z4;
    }

    // ---- stage both x rows as f16 at halo-256 offset (slots 2t+32, 2t+33) ----
    union H8 { _Float16 h[8]; uint4 u; };
    {
        const float* xr0 = x + (size_t)row0 * L_ + 16 * tid;
        const float* xr1 = x + (size_t)row1 * L_ + 16 * tid;
        #pragma unroll
        for (int r = 0; r < 2; r++) {
            const float* xr = r ? xr1 : xr0;
            char* buf = r ? bufB : bufA;
            float4 f0 = *(const float4*)(xr + 0);
            float4 f1 = *(const float4*)(xr + 4);
            float4 f2 = *(const float4*)(xr + 8);
            float4 f3 = *(const float4*)(xr + 12);
            H8 h0, h1;
            h0.h[0] = (_Float16)f0.x; h0.h[1] = (_Float16)f0.y;
            h0.h[2] = (_Float16)f0.z; h0.h[3] = (_Float16)f0.w;
            h0.h[4] = (_Float16)f1.x; h0.h[5] = (_Float16)f1.y;
            h0.h[6] = (_Float16)f1.z; h0.h[7] = (_Float16)f1.w;
            h1.h[0] = (_Float16)f2.x; h1.h[1] = (_Float16)f2.y;
            h1.h[2] = (_Float16)f2.z; h1.h[3] = (_Float16)f2.w;
            h1.h[4] = (_Float16)f3.x; h1.h[5] = (_Float16)f3.y;
            h1.h[6] = (_Float16)f3.z; h1.h[7] = (_Float16)f3.w;
            *(uint4*)(buf + MAPB(2 * tid + 32)) = h0.u;
            *(uint4*)(buf + MAPB(2 * tid + 33)) = h1.u;
        }
    }
    __syncthreads();                                          // S1: x + TAL ready

    // ---- conv51 via 6 MFMAs per row (A51 frags in registers) ----
    f32x16 acc0 = {}, acc1 = {};
    {
        #pragma unroll
        for (int c = 0; c < NCH1; c++) {
            f16x8 a51 = *(const f16x8*)(wsb + A51_OFF + (c * 64 + lane) * 16);
            const int bo = MAPB(128 * w + 4 * j + 2 * c + 28 + hi);
            f16x8 bf0 = *(const f16x8*)(bufA + bo);
            f16x8 bf1 = *(const f16x8*)(bufB + bo);
            acc0 = __builtin_amdgcn_mfma_f32_32x32x16_f16(a51, bf0, acc0, 0, 0, 0);
            acc1 = __builtin_amdgcn_mfma_f32_32x32x16_f16(a51, bf1, acc1, 0, 0, 0);
        }
    }

    // ---- softmax, both rows ----
    float mx0 = -3.402823466e+38f, mx1 = -3.402823466e+38f;
    #pragma unroll
    for (int e = 0; e < 16; e++) { mx0 = fmaxf(mx0, acc0[e]); mx1 = fmaxf(mx1, acc1[e]); }
    #pragma unroll
    for (int o = 32; o > 0; o >>= 1) {
        mx0 = fmaxf(mx0, __shfl_xor(mx0, o));
        mx1 = fmaxf(mx1, __shfl_xor(mx1, o));
    }
    if (lane == 0) { red[w] = mx0; red[8 + w] = mx1; }
    __syncthreads();                                          // S2
    mx0 = red[0]; mx1 = red[8];
    #pragma unroll
    for (int i = 1; i < 8; i++) { mx0 = fmaxf(mx0, red[i]); mx1 = fmaxf(mx1, red[8 + i]); }
    float sm0 = 0.0f, sm1 = 0.0f;
    #pragma unroll
    for (int e = 0; e < 16; e++) {
        acc0[e] = __expf(acc0[e] - mx0); sm0 += acc0[e];
        acc1[e] = __expf(acc1[e] - mx1); sm1 += acc1[e];
    }
    #pragma unroll
    for (int o = 32; o > 0; o >>= 1) { sm0 += __shfl_xor(sm0, o); sm1 += __shfl_xor(sm1, o); }
    if (lane == 0) { red[16 + w] = sm0; red[24 + w] = sm1; }
    __syncthreads();                                          // S3
    float s0 = red[16], s1 = red[24];
    #pragma unroll
    for (int i = 1; i < 8; i++) { s0 += red[16 + i]; s1 += red[24 + i]; }
    const float isum0 = 1.0f / s0, isum1 = 1.0f / s1;

    // ---- write S (f16) via D-layout transpose: e=4k+d -> l = 1024w+32j+8k+4hi+d ----
    union P4 { _Float16 h[4]; uint2 u; };
    #pragma unroll
    for (int k = 0; k < 4; k++) {
        P4 p0, p1;
        #pragma unroll
        for (int d = 0; d < 4; d++) {
            p0.h[d] = (_Float16)(acc0[4 * k + d] * isum0);
            p1.h[d] = (_Float16)(acc1[4 * k + d] * isum1);
        }
        const int bo = MAPB(128 * w + 4 * j + k + 32) + 8 * hi;
        *(uint2*)(bufA + bo) = p0.u;
        *(uint2*)(bufB + bo) = p1.u;
    }
    __syncthreads();                                          // S4: S ready

    // ---- conv501 via 34 chunks; each A-frag feeds both rows' MFMAs ----
    const char* tab6 = wsb + TA_OFF + ((size_t)q * (NCH2 * 64) + lane) * 16;
    f32x16 o0 = {}, o1 = {};
    #pragma unroll
    for (int c = 0; c < NCH2; c++) {
        f16x8 af = (c < TAL_CH)
            ? *(const f16x8*)(TAL + c * 1024 + lane * 16)     // LDS (latency ~120cy)
            : *(const f16x8*)(tab6 + c * 1024);               // L2 tail
        const int bo = MAPB(128 * w + 4 * j + 2 * c + hi);
        f16x8 bf0 = *(const f16x8*)(bufA + bo);
        f16x8 bf1 = *(const f16x8*)(bufB + bo);
        o0 = __builtin_amdgcn_mfma_f32_32x32x16_f16(af, bf0, o0, 0, 0, 0);
        o1 = __builtin_amdgcn_mfma_f32_32x32x16_f16(af, bf1, o1, 0, 0, 0);
    }
    __syncthreads();                                          // S5: S reads done

    // ---- transpose outputs to l-linear (slots 0..1023), coalesced rn store ----
    #pragma unroll
    for (int k = 0; k < 4; k++) {
        P4 p0, p1;
        #pragma unroll
        for (int d = 0; d < 4; d++) {
            p0.h[d] = (_Float16)o0[4 * k + d];
            p1.h[d] = (_Float16)o1[4 * k + d];
        }
        const int bo = MAPB(128 * w + 4 * j + k) + 8 * hi;
        *(uint2*)(bufA + bo) = p0.u;
        *(uint2*)(bufB + bo) = p1.u;
    }
    __syncthreads();                                          // S6
    {
        uint4 r0 = *(uint4*)(bufA + MAPB(2 * tid));
        uint4 r1 = *(uint4*)(bufA + MAPB(2 * tid + 1));
        char* dst = wsb + RN_OFF + ((size_t)row0 * L_ + 16 * tid) * 2;
        *(uint4*)dst = r0;
        *(uint4*)(dst + 16) = r1;
        uint4 r2 = *(uint4*)(bufB + MAPB(2 * tid));
        uint4 r3 = *(uint4*)(bufB + MAPB(2 * tid + 1));
        char* dst1 = wsb + RN_OFF + ((size_t)row1 * L_ + 16 * tid) * 2;
        *(uint4*)dst1 = r2;
        *(uint4*)(dst1 + 16) = r3;
    }
}

// ---------------- kernel 3: serial-q lattice on rn (exact reference scan) ----------------
__global__ __launch_bounds__(256) void k_lat(const float* __restrict__ ws,
                                             float* __restrict__ out) {
    const int tid = threadIdx.x;
    const int T = blockIdx.x & 7, b = blockIdx.x >> 3;
    const char* wsb = (const char*)ws;
    const int l = 1024 * T + 4 * tid;
    const char* src = wsb + RN_OFF + ((size_t)(b * Q_) * L_ + l) * 2;
    float r[4] = {0.0f, 0.0f, 0.0f, 0.0f};
    float t2[4] = {1.0f, 1.0f, 1.0f, 1.0f};
    union P4 { _Float16 h[4]; uint2 u; };
    P4 cur;
    cur.u = *(const uint2*)src;
    for (int q = 0; q < Q_; q++) {
        P4 nxt = cur;
        if (q < Q_ - 1) nxt.u = *(const uint2*)(src + (size_t)(q + 1) * L_ * 2);
        const float aq = ws[q];
        #pragma unroll
        for (int e = 0; e < 4; e++) {
            float rn = (float)cur.h[e], tn = 1.0f - rn;
            float si = 1.0f / (1.0f - aq * r[e] * rn);
            float rnew = r[e] + aq * rn * t2[e] * si;
            t2[e] = aq * t2[e] * tn * tn * si * si;
            r[e] = rnew;
        }
        cur = nxt;
    }
    const float inv_scale = ws[64];
    float4 o;
    o.x = r[0] * inv_scale; o.y = r[1] * inv_scale;
    o.z = r[2] * inv_scale; o.w = r[3] * inv_scale;
    *(float4*)&out[(size_t)b * L_ + l] = o;
}

extern "C" void kernel_launch(void* const* d_in, const int* in_sizes, int n_in,
                              void* d_out, int out_size, void* d_ws, size_t ws_size,
                              hipStream_t stream) {
    (void)in_sizes; (void)n_in; (void)out_size; (void)ws_size;
    const float* x    = (const float*)d_in[0];
    const float* cwh  = (const float*)d_in[1];
    const float* tcw  = (const float*)d_in[2];
    const float* araw = (const float*)d_in[3];
    float* out = (float*)d_out;
    float* ws  = (float*)d_ws;

    hipLaunchKernelGGL(k_params, dim3(Q_ + 1), dim3(256), 0, stream, cwh, tcw, araw, ws);
    hipLaunchKernelGGL(k_fused, dim3((B_ / 2) * Q_), dim3(512), 0, stream, x, ws);
    hipLaunchKernelGGL(k_lat, dim3(B_ * 8), dim3(256), 0, stream, ws, out);
}